// Round 1
// baseline (26722.327 us; speedup 1.0000x reference)
//
#include <hip/hip_runtime.h>
#include <hip/hip_bf16.h>

#define TT 2048
#define DIM 1024
#define HFF 8192
#define NBATCH 4
#define NWG 64
#define THRESH 0.05f

typedef __bf16 bf16x8 __attribute__((ext_vector_type(8)));
typedef float f32x4 __attribute__((ext_vector_type(4)));

__device__ __forceinline__ unsigned short f2bf(float f) {
    __hip_bfloat16 h = __float2bfloat16(f);
    return __builtin_bit_cast(unsigned short, h);
}
__device__ __forceinline__ float bf2f(unsigned short u) {
    return __bfloat162float(__builtin_bit_cast(__hip_bfloat16, u));
}
__device__ __forceinline__ bf16x8 ldf(const unsigned short* p) {
    return *reinterpret_cast<const bf16x8*>(p);
}

// ---------------- mask dtype probe: 1 = int32 mask, 0 = uint8 mask ----------
__global__ void maskprobe_k(const unsigned int* mask_words, int* flag) {
    __shared__ int allok;
    if (threadIdx.x == 0) allok = 1;
    __syncthreads();
    int ok = 1;
    for (int i = 0; i < 16; ++i) {
        unsigned int w = mask_words[threadIdx.x * 16 + i];
        if (w > 1u) ok = 0;
    }
    if (!ok) atomicAnd(&allok, 0);
    __syncthreads();
    if (threadIdx.x == 0) flag[0] = allok;
}

// ---------------- w_eff = syn_w * mask  -> bf16 ----------------
__global__ void weff_k(const float* __restrict__ synw, const void* __restrict__ mask,
                       const int* __restrict__ flag, unsigned short* __restrict__ dst) {
    const int isInt = flag[0];
    const int n = DIM * DIM;
    for (int i = blockIdx.x * 256 + threadIdx.x; i < n; i += gridDim.x * 256) {
        bool m;
        if (isInt) m = ((const int*)mask)[i] != 0;
        else       m = ((const unsigned char*)mask)[i] != 0;
        dst[i] = f2bf(m ? synw[i] : 0.f);
    }
}

// ---------------- f32 -> bf16 convert ----------------
__global__ void conv_k(const float* __restrict__ src, unsigned short* __restrict__ dst, int n) {
    for (int i = blockIdx.x * 256 + threadIdx.x; i < n; i += gridDim.x * 256)
        dst[i] = f2bf(src[i]);
}

// ---------------- f32 -> bf16 hi/lo split ----------------
__global__ void split_k(const float* __restrict__ src, unsigned short* __restrict__ hi,
                        unsigned short* __restrict__ lo, int n) {
    for (int i = blockIdx.x * 256 + threadIdx.x; i < n; i += gridDim.x * 256) {
        float v = src[i];
        unsigned short h = f2bf(v);
        hi[i] = h;
        lo[i] = f2bf(v - bf2f(h));
    }
}

// ---------------- rmsnorm; SPLIT: also emit lo residual ----------------
template <bool SPLIT>
__global__ void rms_k(const float* __restrict__ xin, const float* __restrict__ w,
                      unsigned short* __restrict__ hi, unsigned short* __restrict__ lo) {
    const int row = blockIdx.x;
    const int tid = threadIdx.x;
    const float4 xv = *reinterpret_cast<const float4*>(xin + (size_t)row * DIM + tid * 4);
    float ss = xv.x * xv.x + xv.y * xv.y + xv.z * xv.z + xv.w * xv.w;
    #pragma unroll
    for (int m = 1; m <= 32; m <<= 1) ss += __shfl_xor(ss, m);
    __shared__ float red[5];
    if ((tid & 63) == 0) red[tid >> 6] = ss;
    __syncthreads();
    if (tid == 0) {
        float s = red[0] + red[1] + red[2] + red[3];
        red[4] = 1.f / sqrtf(s * (1.f / DIM) + 1e-6f);
    }
    __syncthreads();
    const float scale = red[4];
    const float wv[4] = {w[tid*4], w[tid*4+1], w[tid*4+2], w[tid*4+3]};
    const float xa[4] = {xv.x, xv.y, xv.z, xv.w};
    #pragma unroll
    for (int i = 0; i < 4; ++i) {
        float v = xa[i] * scale * wv[i];
        unsigned short h = f2bf(v);
        hi[(size_t)row * DIM + tid * 4 + i] = h;
        if constexpr (SPLIT) lo[(size_t)row * DIM + tid * 4 + i] = f2bf(v - bf2f(h));
    }
}

// ---------------- generic MFMA GEMM: C = A @ B^T, A (M,K) bf16, B (N,K) bf16
// EPI 0: U write (hilo A/B; out f32 (T,B,D) + liq_b)    [single B]
// EPI 1: gated residual: x2 = x + acc1*sigmoid(acc2+gb) [dual B]
// EPI 2: swiglu: hbf = bf16(silu(acc1)*acc2)            [dual B]
// EPI 3: out = x2 + acc1                                [single B]
template <int EPI>
__global__ __launch_bounds__(256, 1) void gemm_k(
    const unsigned short* __restrict__ A,  const unsigned short* __restrict__ Alo,
    const unsigned short* __restrict__ B1, const unsigned short* __restrict__ B1lo,
    const unsigned short* __restrict__ B2,
    const float* __restrict__ aux1, const float* __restrict__ aux2,
    float* __restrict__ outf, unsigned short* __restrict__ outbf,
    int M, int N, int K) {
    constexpr bool HILO = (EPI == 0);
    constexpr bool DUAL = (EPI == 1 || EPI == 2);
    const int lane = threadIdx.x & 63;
    const int wv = threadIdx.x >> 6;
    const int l15 = lane & 15, l4 = lane >> 4;
    const long row0 = (long)blockIdx.y * 128 + (wv >> 1) * 64;
    const long col0 = (long)blockIdx.x * 128 + (wv & 1) * 64;
    long aoff[4], boff[4];
    #pragma unroll
    for (int i = 0; i < 4; ++i) {
        aoff[i] = (row0 + i * 16 + l15) * (long)K + l4 * 8;
        boff[i] = (col0 + i * 16 + l15) * (long)K + l4 * 8;
    }
    f32x4 acc[4][4];
    f32x4 acc2[DUAL ? 4 : 1][DUAL ? 4 : 1];
    #pragma unroll
    for (int i = 0; i < 4; ++i)
        #pragma unroll
        for (int j = 0; j < 4; ++j) {
            acc[i][j] = (f32x4){0.f, 0.f, 0.f, 0.f};
            if constexpr (DUAL) acc2[i][j] = (f32x4){0.f, 0.f, 0.f, 0.f};
        }
    for (int kk = 0; kk < K; kk += 32) {
        bf16x8 af[4], bf_[4], al[4], bl[4], b2f[4];
        #pragma unroll
        for (int i = 0; i < 4; ++i) {
            af[i] = ldf(A + aoff[i] + kk);
            bf_[i] = ldf(B1 + boff[i] + kk);
            if constexpr (HILO) {
                al[i] = ldf(Alo + aoff[i] + kk);
                bl[i] = ldf(B1lo + boff[i] + kk);
            }
            if constexpr (DUAL) b2f[i] = ldf(B2 + boff[i] + kk);
        }
        #pragma unroll
        for (int i = 0; i < 4; ++i)
            #pragma unroll
            for (int j = 0; j < 4; ++j) {
                acc[i][j] = __builtin_amdgcn_mfma_f32_16x16x32_bf16(af[i], bf_[j], acc[i][j], 0, 0, 0);
                if constexpr (HILO) {
                    acc[i][j] = __builtin_amdgcn_mfma_f32_16x16x32_bf16(af[i], bl[j], acc[i][j], 0, 0, 0);
                    acc[i][j] = __builtin_amdgcn_mfma_f32_16x16x32_bf16(al[i], bf_[j], acc[i][j], 0, 0, 0);
                }
                if constexpr (DUAL)
                    acc2[i][j] = __builtin_amdgcn_mfma_f32_16x16x32_bf16(af[i], b2f[j], acc2[i][j], 0, 0, 0);
            }
    }
    #pragma unroll
    for (int i = 0; i < 4; ++i) {
        #pragma unroll
        for (int r = 0; r < 4; ++r) {
            const long row = row0 + i * 16 + l4 * 4 + r;
            #pragma unroll
            for (int j = 0; j < 4; ++j) {
                const long col = col0 + j * 16 + l15;
                float v = acc[i][j][r];
                if constexpr (EPI == 0) {
                    int m = (int)row;
                    int bb = m >> 11, tt = m & 2047;
                    outf[((size_t)(tt * NBATCH + bb)) * DIM + col] = v + aux1[col];
                } else if constexpr (EPI == 1) {
                    size_t idx = (size_t)row * N + col;
                    float g = acc2[i][j][r] + aux2[col];
                    outf[idx] = aux1[idx] + v * (1.f / (1.f + expf(-g)));
                } else if constexpr (EPI == 2) {
                    size_t idx = (size_t)row * N + col;
                    float u = acc2[i][j][r];
                    outbf[idx] = f2bf((v / (1.f + expf(-v))) * u);
                } else {
                    size_t idx = (size_t)row * N + col;
                    outf[idx] = aux1[idx] + v;
                }
            }
        }
    }
}

// ---------------- liquid recurrence + PLIF, 64 persistent WGs ----------------
// WG wg owns dims [wg*16, wg*16+16); Wrec slice lives in registers.
// thread t: d_local = t>>4 (0..15), kp = t&15, k-range = [kp*64, kp*64+64)
__global__ __launch_bounds__(256, 1) void recur_k(
    const float* __restrict__ wrec, const float* __restrict__ U,
    const float* __restrict__ liqtau, const float* __restrict__ plifw,
    float* __restrict__ hg, int* __restrict__ cnt, unsigned short* __restrict__ sbf) {
    const int tid = threadIdx.x;
    const int wg = blockIdx.x;
    const int d_local = tid >> 4;
    const int kp = tid & 15;
    const int gdim = wg * 16 + d_local;

    float wreg[64];
    {
        const float* wr = wrec + (size_t)gdim * DIM + kp * 64;
        #pragma unroll
        for (int j = 0; j < 64; j += 4) {
            float4 w4 = *reinterpret_cast<const float4*>(wr + j);
            wreg[j] = w4.x; wreg[j + 1] = w4.y; wreg[j + 2] = w4.z; wreg[j + 3] = w4.w;
        }
    }

    // skewed h staging: [b][k] at b*1088 + (k>>6)*68 + (k&63)
    __shared__ float hl[4 * 1088];
    for (int i = tid; i < 4 * 1088; i += 256) hl[i] = 0.f;

    const float decay = 1.f / (1.f + expf(-plifw[0]));
    const bool lead = (kp == 0);
    float hreg[4] = {0.f, 0.f, 0.f, 0.f};
    float vreg[4] = {0.f, 0.f, 0.f, 0.f};
    float tauv = 1.f;
    if (lead) {
        float lt = liqtau[gdim];
        tauv = (lt > 20.f) ? lt : log1pf(expf(lt));
    }
    __syncthreads();

    const float* hb = hl + kp * 68;
    for (int t = 0; t < TT; ++t) {
        float a0 = 0.f, a1 = 0.f, a2 = 0.f, a3 = 0.f;
        #pragma unroll
        for (int j4 = 0; j4 < 16; ++j4) {
            const int ko = j4 * 4;
            const float4 h0 = *reinterpret_cast<const float4*>(hb + ko);
            const float4 h1 = *reinterpret_cast<const float4*>(hb + 1088 + ko);
            const float4 h2 = *reinterpret_cast<const float4*>(hb + 2176 + ko);
            const float4 h3 = *reinterpret_cast<const float4*>(hb + 3264 + ko);
            a0 = fmaf(wreg[ko], h0.x, a0); a0 = fmaf(wreg[ko+1], h0.y, a0);
            a0 = fmaf(wreg[ko+2], h0.z, a0); a0 = fmaf(wreg[ko+3], h0.w, a0);
            a1 = fmaf(wreg[ko], h1.x, a1); a1 = fmaf(wreg[ko+1], h1.y, a1);
            a1 = fmaf(wreg[ko+2], h1.z, a1); a1 = fmaf(wreg[ko+3], h1.w, a1);
            a2 = fmaf(wreg[ko], h2.x, a2); a2 = fmaf(wreg[ko+1], h2.y, a2);
            a2 = fmaf(wreg[ko+2], h2.z, a2); a2 = fmaf(wreg[ko+3], h2.w, a2);
            a3 = fmaf(wreg[ko], h3.x, a3); a3 = fmaf(wreg[ko+1], h3.y, a3);
            a3 = fmaf(wreg[ko+2], h3.z, a3); a3 = fmaf(wreg[ko+3], h3.w, a3);
        }
        #pragma unroll
        for (int m = 1; m <= 8; m <<= 1) {
            a0 += __shfl_xor(a0, m); a1 += __shfl_xor(a1, m);
            a2 += __shfl_xor(a2, m); a3 += __shfl_xor(a3, m);
        }
        if (lead) {
            const float accs[4] = {a0, a1, a2, a3};
            #pragma unroll
            for (int b = 0; b < 4; ++b) {
                float pre = accs[b] + U[((size_t)t * NBATCH + b) * DIM + gdim];
                float th = tanhf(pre);
                float hn = hreg[b] + (th - hreg[b]) / tauv;
                hreg[b] = hn;
                float v = vreg[b] + decay * (hn - vreg[b]);
                float s = ((v - THRESH) > 0.f) ? 1.f : 0.f;
                vreg[b] = v - s * THRESH;
                sbf[((size_t)b * TT + t) * DIM + gdim] = (s > 0.f) ? (unsigned short)0x3F80 : (unsigned short)0;
                __hip_atomic_store(&hg[(size_t)(t & 1) * 4096 + b * DIM + gdim], hn,
                                   __ATOMIC_RELAXED, __HIP_MEMORY_SCOPE_AGENT);
            }
        }
        if (t == TT - 1) break;
        __syncthreads();  // drains vmcnt -> h stores globally visible
        if (tid == 0) {
            __hip_atomic_fetch_add(&cnt[t], 1, __ATOMIC_RELEASE, __HIP_MEMORY_SCOPE_AGENT);
            while (__hip_atomic_load(&cnt[t], __ATOMIC_ACQUIRE, __HIP_MEMORY_SCOPE_AGENT) < NWG)
                __builtin_amdgcn_s_sleep(1);
        }
        __syncthreads();
        {
            const float* src = hg + (size_t)(t & 1) * 4096;
            #pragma unroll
            for (int j = 0; j < 16; ++j) {
                int g = tid + j * 256;
                float v = __hip_atomic_load(&src[g], __ATOMIC_RELAXED, __HIP_MEMORY_SCOPE_AGENT);
                int b = g >> 10, k = g & 1023;
                hl[b * 1088 + (k >> 6) * 68 + (k & 63)] = v;
            }
        }
        __syncthreads();
    }
}

extern "C" void kernel_launch(void* const* d_in, const int* in_sizes, int n_in,
                              void* d_out, int out_size, void* d_ws, size_t ws_size,
                              hipStream_t stream) {
    (void)in_sizes; (void)n_in; (void)out_size; (void)ws_size;
    const float* x     = (const float*)d_in[0];
    const float* ln1   = (const float*)d_in[1];
    const float* win   = (const float*)d_in[2];
    const float* wrec  = (const float*)d_in[3];
    const float* liqb  = (const float*)d_in[4];
    const float* liqtau= (const float*)d_in[5];
    const float* plifw = (const float*)d_in[6];
    const float* synw  = (const float*)d_in[7];
    const float* gatew = (const float*)d_in[8];
    const float* gateb = (const float*)d_in[9];
    const float* ln2   = (const float*)d_in[10];
    const float* wgp   = (const float*)d_in[11];
    const float* wup   = (const float*)d_in[12];
    const float* wdp   = (const float*)d_in[13];
    const void*  mask  = d_in[14];
    float* dout = (float*)d_out;
    char* ws = (char*)d_ws;
    const size_t MB = (size_t)1 << 20;

    unsigned short* winh  = (unsigned short*)(ws + 0 * MB);
    unsigned short* winl  = (unsigned short*)(ws + 2 * MB);
    unsigned short* weffb = (unsigned short*)(ws + 4 * MB);
    unsigned short* gatewb= (unsigned short*)(ws + 6 * MB);
    unsigned short* wgb   = (unsigned short*)(ws + 8 * MB);
    unsigned short* wub   = (unsigned short*)(ws + 24 * MB);
    unsigned short* wdb   = (unsigned short*)(ws + 40 * MB);
    unsigned short* ahi   = (unsigned short*)(ws + 56 * MB);   // reused as y_bf
    unsigned short* alo   = (unsigned short*)(ws + 72 * MB);
    float*          Ubuf  = (float*)(ws + 88 * MB);            // reused as hff chunk
    unsigned short* hffb  = (unsigned short*)(ws + 88 * MB);
    unsigned short* sbf   = (unsigned short*)(ws + 120 * MB);
    float*          x2    = (float*)(ws + 136 * MB);
    float*          hgb   = (float*)(ws + 168 * MB);           // 32 KB
    int*            cnt   = (int*)(ws + 168 * MB + 64 * 1024); // 8 KB
    int*            flag  = (int*)(ws + 168 * MB + 80 * 1024);

    hipMemsetAsync(cnt, 0, TT * sizeof(int), stream);
    maskprobe_k<<<1, 256, 0, stream>>>((const unsigned int*)mask, flag);
    weff_k<<<1024, 256, 0, stream>>>(synw, mask, flag, weffb);
    split_k<<<1024, 256, 0, stream>>>(win, winh, winl, DIM * DIM);
    conv_k<<<1024, 256, 0, stream>>>(gatew, gatewb, DIM * DIM);
    conv_k<<<2048, 256, 0, stream>>>(wgp, wgb, HFF * DIM);
    conv_k<<<2048, 256, 0, stream>>>(wup, wub, HFF * DIM);
    conv_k<<<2048, 256, 0, stream>>>(wdp, wdb, DIM * HFF);

    rms_k<true><<<NBATCH * TT, 256, 0, stream>>>(x, ln1, ahi, alo);
    gemm_k<0><<<dim3(DIM / 128, (NBATCH * TT) / 128), 256, 0, stream>>>(
        ahi, alo, winh, winl, nullptr, liqb, nullptr, Ubuf, nullptr,
        NBATCH * TT, DIM, DIM);

    recur_k<<<NWG, 256, 0, stream>>>(wrec, Ubuf, liqtau, plifw, hgb, cnt, sbf);

    gemm_k<1><<<dim3(DIM / 128, (NBATCH * TT) / 128), 256, 0, stream>>>(
        sbf, nullptr, weffb, nullptr, gatewb, x, gateb, x2, nullptr,
        NBATCH * TT, DIM, DIM);

    rms_k<false><<<NBATCH * TT, 256, 0, stream>>>(x2, ln2, ahi, nullptr);

    const int CH = 2048;  // FFN row-chunk to bound hff scratch to 32 MB
    for (int c = 0; c < (NBATCH * TT) / CH; ++c) {
        const size_t ro = (size_t)c * CH;
        gemm_k<2><<<dim3(HFF / 128, CH / 128), 256, 0, stream>>>(
            ahi + ro * DIM, nullptr, wgb, nullptr, wub, nullptr, nullptr,
            nullptr, hffb, CH, HFF, DIM);
        gemm_k<3><<<dim3(DIM / 128, CH / 128), 256, 0, stream>>>(
            hffb, nullptr, wdb, nullptr, nullptr, x2 + ro * DIM, nullptr,
            dout + ro * DIM, nullptr, CH, DIM, HFF);
    }
}